// Round 7
// baseline (41248.337 us; speedup 1.0000x reference)
//
#include <hip/hip_runtime.h>
#include <hip/hip_cooperative_groups.h>

// Problem constants (B=2, S=1024, I=1024, H=1024, L=2)
constexpr int HD    = 1024;       // hidden size == input size
constexpr int SEQ   = 2048;       // B*S flattened steps per layer
constexpr int NL    = 2;          // layers
constexpr int NSTEP = NL * SEQ;   // 4096 serial steps
constexpr int NWG   = 256;        // workgroups (1 per CU)
constexpr int TPB   = 256;        // threads per block
constexpr int RPW   = HD / NWG;   // rows owned per WG = 4
constexpr int NMIR  = 32;         // mirror copies (8 pollers per mirror line)

typedef unsigned u32x4 __attribute__((ext_vector_type(4)));

// ---------------------------------------------------------------------------
// Packed-element dataflow, 32-way mirrored. Element = 4 B =
// (u16 step-tag <<16 | bf16 value); the store is both data and readiness
// signal. Round-6 showed per-line poller count is the lever (8x cut -> 1.4x);
// this round cuts it another 4x (32 mirrors) and halves detection
// quantization with a 2-deep pipelined poll (sample every ~RT/2).
// ---------------------------------------------------------------------------
__device__ __forceinline__ unsigned packbf(float v, unsigned tag) {
  unsigned b = __float_as_uint(v);
  b += 0x7FFFu + ((b >> 16) & 1u);          // RNE round to bf16
  return (tag << 16) | (b >> 16);
}
__device__ __forceinline__ float unpackbf(unsigned w) {
  return __uint_as_float(w << 16);
}
// Multicast one element to all 32 mirrors (stride HD u32 = 4KB), staggered
// start so concurrent producers don't all hammer mirror 0 first.
__device__ __forceinline__ void store_mcast(unsigned* base, unsigned w, int start) {
#pragma unroll
  for (int m = 0; m < NMIR; ++m) {
    const int mir = (m + start) & (NMIR - 1);
    __hip_atomic_store(base + mir * HD, w, __ATOMIC_RELAXED, __HIP_MEMORY_SCOPE_AGENT);
  }
}

// 2-deep pipelined poll of 4 packed elements (16B): two loads in flight,
// vmcnt(1) ping-pong -> sampling interval ~RT/2 instead of RT+sleep.
// sched_barrier(0) after each waitcnt: "memory" clobber does NOT order the
// register-only tag checks (guide rule #18).
__device__ __forceinline__ u32x4 poll4(const unsigned* p, unsigned tag) {
  u32x4 a, b;
  asm volatile("global_load_dwordx4 %0, %1, off sc0 sc1"
               : "=&v"(a) : "v"(p) : "memory");
  while (true) {
    asm volatile("global_load_dwordx4 %0, %1, off sc0 sc1\n\t"
                 "s_waitcnt vmcnt(1)"
                 : "=&v"(b) : "v"(p) : "memory");
    __builtin_amdgcn_sched_barrier(0);       // 'a' is valid only after here
    if ((a.x >> 16) == tag && (a.y >> 16) == tag &&
        (a.z >> 16) == tag && (a.w >> 16) == tag) {
      asm volatile("s_waitcnt vmcnt(0)" : "+v"(b) :: "memory");  // drain b
      return a;
    }
    asm volatile("global_load_dwordx4 %0, %1, off sc0 sc1\n\t"
                 "s_waitcnt vmcnt(1)"
                 : "=&v"(a) : "v"(p) : "memory");
    __builtin_amdgcn_sched_barrier(0);       // 'b' is valid only after here
    if ((b.x >> 16) == tag && (b.y >> 16) == tag &&
        (b.z >> 16) == tag && (b.w >> 16) == tag) {
      asm volatile("s_waitcnt vmcnt(0)" : "+v"(a) :: "memory");  // drain a
      return b;
    }
  }
}

// ---------------------------------------------------------------------------
// Phase A: Ax[gl][t][row] = X[t,:] . W_g[l][row, HD:2HD] + b_g[l][row]
// gl = l*3 + g, g in {0:r, 1:z, 2:h}. 64x64 fp32 LDS-tiled GEMM (unchanged).
// ---------------------------------------------------------------------------
__global__ void __launch_bounds__(256) ax_gemm_kernel(
    const float* __restrict__ X,
    const float* __restrict__ Wr, const float* __restrict__ Wz, const float* __restrict__ Wh,
    const float* __restrict__ br, const float* __restrict__ bz, const float* __restrict__ bh,
    float* __restrict__ ax)
{
  __shared__ float sX[16][64];   // [k][t]
  __shared__ float sW[16][64];   // [k][row]

  const int gl = blockIdx.z, l = gl / 3, g = gl % 3;
  const float* W    = (g == 0 ? Wr : (g == 1 ? Wz : Wh)) + (size_t)l * HD * (2 * HD) + HD;
  const float* bias = (g == 0 ? br : (g == 1 ? bz : bh)) + l * HD;
  const int t0 = blockIdx.y * 64, r0 = blockIdx.x * 64;
  const int tid = threadIdx.x;
  const int tx = tid & 15;        // row micro-tile index
  const int ty = tid >> 4;        // t  micro-tile index
  const int lt = tid >> 2;        // staging local row 0..63
  const int lk = (tid & 3) * 4;   // staging k offset {0,4,8,12}

  float acc[4][4] = {};           // [i: t][j: row]

  for (int k0 = 0; k0 < HD; k0 += 16) {
    float4 xv = *reinterpret_cast<const float4*>(&X[(size_t)(t0 + lt) * HD + k0 + lk]);
    float4 wv = *reinterpret_cast<const float4*>(&W[(size_t)(r0 + lt) * (2 * HD) + k0 + lk]);
    __syncthreads();
    sX[lk + 0][lt] = xv.x; sX[lk + 1][lt] = xv.y; sX[lk + 2][lt] = xv.z; sX[lk + 3][lt] = xv.w;
    sW[lk + 0][lt] = wv.x; sW[lk + 1][lt] = wv.y; sW[lk + 2][lt] = wv.z; sW[lk + 3][lt] = wv.w;
    __syncthreads();
#pragma unroll
    for (int k = 0; k < 16; ++k) {
      float4 a = *reinterpret_cast<const float4*>(&sX[k][ty * 4]);
      float4 b = *reinterpret_cast<const float4*>(&sW[k][tx * 4]);
      const float av[4] = {a.x, a.y, a.z, a.w};
      const float bv[4] = {b.x, b.y, b.z, b.w};
#pragma unroll
      for (int i = 0; i < 4; ++i)
#pragma unroll
        for (int j = 0; j < 4; ++j)
          acc[i][j] += av[i] * bv[j];
    }
  }

  float4 bb = *reinterpret_cast<const float4*>(&bias[r0 + tx * 4]);
  const float bv[4] = {bb.x, bb.y, bb.z, bb.w};
#pragma unroll
  for (int i = 0; i < 4; ++i) {
    float4 o;
    o.x = acc[i][0] + bv[0]; o.y = acc[i][1] + bv[1];
    o.z = acc[i][2] + bv[2]; o.w = acc[i][3] + bv[3];
    *reinterpret_cast<float4*>(
        &ax[((size_t)gl * SEQ + t0 + ty * 4 + i) * HD + r0 + tx * 4]) = o;
  }
}

// ---------------------------------------------------------------------------
// Phase B: 4096-step serial scan, barrier-free packed dataflow, 32x mirrored.
// hpack / rhpack layout: [2 slots][32 mirrors][1024 u32] (256 KB each).
//   h entering step u : slot u&1,     tag u    (memset 0 == step-0 init, h=0)
//   r*h of step u     : slot u&1,     tag u+1
//   h leaving step u  : slot (u+1)&1, tag u+1
// Per step: phase1 = {poll h, r-dot, publish r*h, z-dot in store shadow},
//           phase2 = {poll r*h, hh-dot, blend, publish h}.
// All gate dots: 4 rows x 64 lanes. fp32 h-carry in sHF32 (own rows only).
// Prefetches (axh, nax_*) are issued AFTER each poll so the poll's vmcnt(1)
// never force-drains an in-flight HBM prefetch.
// ---------------------------------------------------------------------------
__global__ void __launch_bounds__(TPB) gru_seq_kernel(
    const float* __restrict__ Wr, const float* __restrict__ Wz, const float* __restrict__ Wh,
    const float* __restrict__ ax,
    unsigned* __restrict__ hpack, unsigned* __restrict__ rhpack,
    float* __restrict__ outp)
{
  __shared__ float sW[NL][3][RPW][HD];  // 96 KB: h-part weight rows (fp32)
  __shared__ float sVecH[HD];           // staged h (read by r- and z-dots)
  __shared__ float sVecRH[HD];          // staged r*h (read by hh-dot)
  __shared__ float sHF32[RPW];          // OWN h rows, fp32 carry (never bf16)
  __shared__ float sAxRZ[2 * RPW];      // ax for r,z rows, current step
  __shared__ float sAxH[RPW];           // ax for hh rows, current step
  __shared__ float sZ[RPW];

  const int wg = blockIdx.x;
  const int tid = threadIdx.x;
  const int row0 = wg * RPW;
  const int mymir = wg >> 3;            // 8 WGs share one mirror
  const int mstart = wg & (NMIR - 1);   // staggered mcast start

  // Stage weights once: h-part = columns [0, HD) of W_g[l][row]
  for (int f = tid; f < NL * 3 * RPW * HD; f += TPB) {
    const int k  = f & (HD - 1);
    const int rr = f >> 10;          // 0..23
    const int r  = rr & 3;
    const int g  = (rr >> 2) % 3;
    const int l  = (rr >> 2) / 3;
    const float* W = (g == 0 ? Wr : (g == 1 ? Wz : Wh));
    sW[l][g][r][k] = W[((size_t)l * HD + row0 + r) * (2 * HD) + k];
  }
  if (tid < RPW) sHF32[tid] = 0.0f;    // h0 = 0 (own rows, fp32)
  __syncthreads();

  // Prologue: prefetch ax_r / ax_z for step 0 (consumed in first phase 1)
  float4 nax_r, nax_z, axh;
  if (tid == 0) {
    nax_r = *reinterpret_cast<const float4*>(&ax[(size_t)0 * SEQ * HD + row0]);
    nax_z = *reinterpret_cast<const float4*>(&ax[(size_t)1 * SEQ * HD + row0]);
  }

  for (int u = 0; u < NSTEP; ++u) {
    const int l = u >> 11;           // layer
    const int t = u & (SEQ - 1);     // step within layer
    const int slot  = (u & 1) * NMIR * HD;
    const int slotn = ((u + 1) & 1) * NMIR * HD;

    // ---- phase 1: poll h; r-dot; publish r*h; z-dot in store shadow -----
    if (tid == 0) {   // publish r/z ax values prefetched during previous phase
      sAxRZ[0] = nax_r.x; sAxRZ[1] = nax_r.y; sAxRZ[2] = nax_r.z; sAxRZ[3] = nax_r.w;
      sAxRZ[4] = nax_z.x; sAxRZ[5] = nax_z.y; sAxRZ[6] = nax_z.z; sAxRZ[7] = nax_z.w;
    }
    u32x4 hv = poll4(&hpack[slot + mymir * HD + 4 * tid], (unsigned)u);
    sVecH[4 * tid + 0] = unpackbf(hv.x);
    sVecH[4 * tid + 1] = unpackbf(hv.y);
    sVecH[4 * tid + 2] = unpackbf(hv.z);
    sVecH[4 * tid + 3] = unpackbf(hv.w);
    if (tid == 0) {   // issue ax_h for THIS step (consumed phase 2) AFTER poll
      axh = *reinterpret_cast<const float4*>(
          &ax[(((size_t)l * 3 + 2) * SEQ + t) * HD + row0]);
    }
    __syncthreads();
    {
      const int task = tid >> 6;       // 0..3 (4 rows), 64 lanes each
      const int lane = tid & 63;
      // r-dot first: get r*h flying ASAP
      const float* wr_ = sW[l][0][task];
      float sum = 0.0f;
#pragma unroll 8
      for (int k = lane; k < HD; k += 64) sum += wr_[k] * sVecH[k];
#pragma unroll
      for (int off = 32; off; off >>= 1) sum += __shfl_down(sum, off);
      if (lane == 0) {
        const float r = 1.0f / (1.0f + expf(-(sum + sAxRZ[task])));
        store_mcast(rhpack + slot + row0 + task,
                    packbf(r * sHF32[task], (unsigned)(u + 1)), mstart);
      }
      // z-dot runs while the r*h stores fly (result needed only in phase 2)
      const float* wz_ = sW[l][1][task];
      float sz = 0.0f;
#pragma unroll 8
      for (int k = lane; k < HD; k += 64) sz += wz_[k] * sVecH[k];
#pragma unroll
      for (int off = 32; off; off >>= 1) sz += __shfl_down(sz, off);
      if (lane == 0)
        sZ[task] = 1.0f / (1.0f + expf(-(sz + sAxRZ[4 + task])));
    }

    // ---- phase 2: poll r*h; hh-dot; blend; publish h ---------------------
    if (tid == 0) {   // publish ax_h issued in phase 1 (long since complete)
      sAxH[0] = axh.x; sAxH[1] = axh.y; sAxH[2] = axh.z; sAxH[3] = axh.w;
    }
    u32x4 rv = poll4(&rhpack[slot + mymir * HD + 4 * tid], (unsigned)(u + 1));
    sVecRH[4 * tid + 0] = unpackbf(rv.x);
    sVecRH[4 * tid + 1] = unpackbf(rv.y);
    sVecRH[4 * tid + 2] = unpackbf(rv.z);
    sVecRH[4 * tid + 3] = unpackbf(rv.w);
    if (tid == 0) {   // prefetch next step's ax_r/ax_z AFTER poll
      const int un = (u + 1 < NSTEP) ? u + 1 : u;
      const int ln = un >> 11, tn = un & (SEQ - 1);
      nax_r = *reinterpret_cast<const float4*>(
          &ax[(((size_t)ln * 3 + 0) * SEQ + tn) * HD + row0]);
      nax_z = *reinterpret_cast<const float4*>(
          &ax[(((size_t)ln * 3 + 1) * SEQ + tn) * HD + row0]);
    }
    __syncthreads();
    {
      const int task = tid >> 6;       // 0..3 (hh rows), 64 lanes each
      const int lane = tid & 63;
      const float* wh_ = sW[l][2][task];
      float sum = 0.0f;
#pragma unroll 8
      for (int k = lane; k < HD; k += 64) sum += wh_[k] * sVecRH[k];
#pragma unroll
      for (int off = 32; off; off >>= 1) sum += __shfl_down(sum, off);
      if (lane == 0) {
        const float hh = tanhf(sum + sAxH[task]);
        const float z = sZ[task];
        const float hn = (1.0f - z) * sHF32[task] + z * hh;   // fp32 carry
        sHF32[task] = hn;
        store_mcast(hpack + slotn + row0 + task,
                    packbf(hn, (unsigned)(u + 1)), mstart);
        if (u == NSTEP - 1) {          // (output, hidden) identical
          outp[row0 + task] = hn;
          outp[HD + row0 + task] = hn;
        }
      }
    }
  }
}

// ---------------------------------------------------------------------------
extern "C" void kernel_launch(void* const* d_in, const int* in_sizes, int n_in,
                              void* d_out, int out_size, void* d_ws, size_t ws_size,
                              hipStream_t stream) {
  const float* emb = (const float*)d_in[0];
  const float* Wr  = (const float*)d_in[1];
  const float* br  = (const float*)d_in[2];
  const float* Wz  = (const float*)d_in[3];
  const float* bz  = (const float*)d_in[4];
  const float* Wh  = (const float*)d_in[5];
  const float* bh  = (const float*)d_in[6];
  float* outp = (float*)d_out;

  float*    ws     = (float*)d_ws;
  float*    ax     = ws;                                // 6*SEQ*HD fp32 = 50.3 MB
  unsigned* hpack  = (unsigned*)(ws + (size_t)6 * SEQ * HD); // 2*32*1024 u32 = 256 KB
  unsigned* rhpack = hpack + 2 * NMIR * HD;             // 256 KB

  // Deterministic tag state each call: zero both parities of both mirrored
  // pack buffers (slot0 tag=0 == "h entering step 0", value bf16(0)).
  hipMemsetAsync(hpack, 0, 4 * NMIR * HD * sizeof(unsigned), stream);

  // Phase A: x-part contributions + bias, all gates/layers (parallel GEMM)
  dim3 g1(HD / 64, SEQ / 64, 6);
  ax_gemm_kernel<<<g1, 256, 0, stream>>>(emb, Wr, Wz, Wh, br, bz, bh, ax);

  // Phase B: serial scan; cooperative launch only for the co-residency
  // guarantee (mirrored tagged dataflow replaces all barriers).
  void* args[] = {(void*)&Wr, (void*)&Wz, (void*)&Wh, (void*)&ax,
                  (void*)&hpack, (void*)&rhpack, (void*)&outp};
  hipLaunchCooperativeKernel((const void*)gru_seq_kernel, dim3(NWG), dim3(TPB),
                             args, 0, stream);
}

// Round 8
// 24688.051 us; speedup vs baseline: 1.6708x; 1.6708x over previous
//
#include <hip/hip_runtime.h>
#include <hip/hip_cooperative_groups.h>

// Problem constants (B=2, S=1024, I=1024, H=1024, L=2)
constexpr int HD    = 1024;       // hidden size == input size
constexpr int SEQ   = 2048;       // B*S flattened steps per layer
constexpr int NL    = 2;          // layers
constexpr int NSTEP = NL * SEQ;   // 4096 serial steps
constexpr int NWG   = 256;        // workgroups (1 per CU, bijective)
constexpr int TPB   = 320;        // 4 compute waves + 1 relay wave
constexpr int CTH   = 256;        // compute threads per block
constexpr int RPW   = HD / NWG;   // rows owned per WG = 4
constexpr int NXCD  = 8;          // XCDs

typedef unsigned u32x4 __attribute__((ext_vector_type(4)));

// ---------------------------------------------------------------------------
// Hierarchical tagged dataflow. Element = 4 B = (u16 step-tag <<16 | bf16).
// Producers mcast to 8 MALL "home" buffers (one per XCD). Per XCD, ONE
// elected relay wave is the sole poller of its home (uncontended visibility,
// tiny MALL read traffic) and republishes raw words into a per-XCD local
// mirror with sc0-only stores; the XCD's 32 consumer WGs poll the mirror
// with sc0-only loads served by their shared XCD L2 (no MALL/HBM traffic).
// Round-7 lesson: sc0sc1 poll/store traffic hits HBM and scales with poll
// rate x footprint — so concentrate MALL polling into 8 waves total.
// Fallback: every 8th failed consumer poll checks the MALL home directly,
// so correctness never depends on same-XCD L2 forwarding.
// ---------------------------------------------------------------------------
__device__ __forceinline__ unsigned packbf(float v, unsigned tag) {
  unsigned b = __float_as_uint(v);
  b += 0x7FFFu + ((b >> 16) & 1u);          // RNE round to bf16
  return (tag << 16) | (b >> 16);
}
__device__ __forceinline__ float unpackbf(unsigned w) {
  return __uint_as_float(w << 16);
}
__device__ __forceinline__ bool tags_ok(u32x4 v, unsigned tag) {
  return (v.x >> 16) == tag && (v.y >> 16) == tag &&
         (v.z >> 16) == tag && (v.w >> 16) == tag;
}
// Consumer poll: fast path = local mirror via sc0 (XCD L2); every 8th failed
// round checks the MALL home (sc0 sc1) as a correctness fallback.
__device__ __forceinline__ u32x4 cpoll(const unsigned* lp, const unsigned* hp,
                                       unsigned tag) {
  while (true) {
#pragma unroll 1
    for (int i = 0; i < 8; ++i) {
      u32x4 v;
      asm volatile("global_load_dwordx4 %0, %1, off sc0\n\ts_waitcnt vmcnt(0)"
                   : "=v"(v) : "v"(lp) : "memory");
      if (tags_ok(v, tag)) return v;
      __builtin_amdgcn_s_sleep(1);
    }
    u32x4 v;
    asm volatile("global_load_dwordx4 %0, %1, off sc0 sc1\n\ts_waitcnt vmcnt(0)"
                 : "=v"(v) : "v"(hp) : "memory");
    if (tags_ok(v, tag)) return v;
  }
}
// Relay: lane owns 16 elements (64B). Poll home (sole MALL poller), forward
// each ready 16B chunk into the local mirror with an sc0 store (raw words,
// tags travel with the data; per-dword atomicity makes tearing safe).
__device__ __forceinline__ void relay_forward(const unsigned* src, unsigned* dst,
                                              unsigned tag, int lane) {
  const unsigned* s = src + lane * 16;
  unsigned* d = dst + lane * 16;
  unsigned done = 0;
  while (done != 0xFu) {
    u32x4 v0, v1, v2, v3;
    asm volatile(
        "global_load_dwordx4 %0, %4, off sc0 sc1\n\t"
        "global_load_dwordx4 %1, %4, off offset:16 sc0 sc1\n\t"
        "global_load_dwordx4 %2, %4, off offset:32 sc0 sc1\n\t"
        "global_load_dwordx4 %3, %4, off offset:48 sc0 sc1\n\t"
        "s_waitcnt vmcnt(0)"
        : "=&v"(v0), "=&v"(v1), "=&v"(v2), "=&v"(v3)
        : "v"(s) : "memory");
    if (!(done & 1u) && tags_ok(v0, tag)) {
      asm volatile("global_store_dwordx4 %0, %1, off sc0" :: "v"(d), "v"(v0) : "memory");
      done |= 1u;
    }
    if (!(done & 2u) && tags_ok(v1, tag)) {
      asm volatile("global_store_dwordx4 %0, %1, off sc0" :: "v"(d + 4), "v"(v1) : "memory");
      done |= 2u;
    }
    if (!(done & 4u) && tags_ok(v2, tag)) {
      asm volatile("global_store_dwordx4 %0, %1, off sc0" :: "v"(d + 8), "v"(v2) : "memory");
      done |= 4u;
    }
    if (!(done & 8u) && tags_ok(v3, tag)) {
      asm volatile("global_store_dwordx4 %0, %1, off sc0" :: "v"(d + 12), "v"(v3) : "memory");
      done |= 8u;
    }
    if (done != 0xFu) __builtin_amdgcn_s_sleep(1);
  }
}
// Producer publish: one element to all 8 XCD homes (stagger start by wg).
__device__ __forceinline__ void publish(unsigned* base, unsigned w, int start) {
#pragma unroll
  for (int x = 0; x < NXCD; ++x)
    __hip_atomic_store(base + ((x + start) & (NXCD - 1)) * HD, w,
                       __ATOMIC_RELAXED, __HIP_MEMORY_SCOPE_AGENT);
}

// ---------------------------------------------------------------------------
// Phase A: Ax[gl][t][row] = X[t,:] . W_g[l][row, HD:2HD] + b_g[l][row]
// gl = l*3 + g, g in {0:r, 1:z, 2:h}. 64x64 fp32 LDS-tiled GEMM (unchanged).
// ---------------------------------------------------------------------------
__global__ void __launch_bounds__(256) ax_gemm_kernel(
    const float* __restrict__ X,
    const float* __restrict__ Wr, const float* __restrict__ Wz, const float* __restrict__ Wh,
    const float* __restrict__ br, const float* __restrict__ bz, const float* __restrict__ bh,
    float* __restrict__ ax)
{
  __shared__ float sX[16][64];   // [k][t]
  __shared__ float sW[16][64];   // [k][row]

  const int gl = blockIdx.z, l = gl / 3, g = gl % 3;
  const float* W    = (g == 0 ? Wr : (g == 1 ? Wz : Wh)) + (size_t)l * HD * (2 * HD) + HD;
  const float* bias = (g == 0 ? br : (g == 1 ? bz : bh)) + l * HD;
  const int t0 = blockIdx.y * 64, r0 = blockIdx.x * 64;
  const int tid = threadIdx.x;
  const int tx = tid & 15;        // row micro-tile index
  const int ty = tid >> 4;        // t  micro-tile index
  const int lt = tid >> 2;        // staging local row 0..63
  const int lk = (tid & 3) * 4;   // staging k offset {0,4,8,12}

  float acc[4][4] = {};           // [i: t][j: row]

  for (int k0 = 0; k0 < HD; k0 += 16) {
    float4 xv = *reinterpret_cast<const float4*>(&X[(size_t)(t0 + lt) * HD + k0 + lk]);
    float4 wv = *reinterpret_cast<const float4*>(&W[(size_t)(r0 + lt) * (2 * HD) + k0 + lk]);
    __syncthreads();
    sX[lk + 0][lt] = xv.x; sX[lk + 1][lt] = xv.y; sX[lk + 2][lt] = xv.z; sX[lk + 3][lt] = xv.w;
    sW[lk + 0][lt] = wv.x; sW[lk + 1][lt] = wv.y; sW[lk + 2][lt] = wv.z; sW[lk + 3][lt] = wv.w;
    __syncthreads();
#pragma unroll
    for (int k = 0; k < 16; ++k) {
      float4 a = *reinterpret_cast<const float4*>(&sX[k][ty * 4]);
      float4 b = *reinterpret_cast<const float4*>(&sW[k][tx * 4]);
      const float av[4] = {a.x, a.y, a.z, a.w};
      const float bv[4] = {b.x, b.y, b.z, b.w};
#pragma unroll
      for (int i = 0; i < 4; ++i)
#pragma unroll
        for (int j = 0; j < 4; ++j)
          acc[i][j] += av[i] * bv[j];
    }
  }

  float4 bb = *reinterpret_cast<const float4*>(&bias[r0 + tx * 4]);
  const float bv[4] = {bb.x, bb.y, bb.z, bb.w};
#pragma unroll
  for (int i = 0; i < 4; ++i) {
    float4 o;
    o.x = acc[i][0] + bv[0]; o.y = acc[i][1] + bv[1];
    o.z = acc[i][2] + bv[2]; o.w = acc[i][3] + bv[3];
    *reinterpret_cast<float4*>(
        &ax[((size_t)gl * SEQ + t0 + ty * 4 + i) * HD + r0 + tx * 4]) = o;
  }
}

// ---------------------------------------------------------------------------
// Phase B: 4096-step serial scan, relay-hierarchical tagged dataflow.
// home_h/home_rh : [2 parity][8 xcd][1024 u32]  (MALL; producers mcast)
// lmir_h/lmir_rh : [2 parity][8 xcd][1024 u32]  (per-XCD L2 working copies)
//   h entering step u : parity u&1, tag u   (memset 0 == step-0 init, h=0)
//   r*h of step u     : parity u&1, tag u+1
//   h leaving step u  : parity (u+1)&1, tag u+1
// Waves 0-3 compute (4 rows each of r/z/hh, 64 lanes per row); wave 4 is the
// relay in the 8 elected WGs (atomicCAS per XCD), idle barrier-matcher
// elsewhere. 2 __syncthreads per step in every wave.
// ---------------------------------------------------------------------------
__global__ void __launch_bounds__(TPB) gru_seq_kernel(
    const float* __restrict__ Wr, const float* __restrict__ Wz, const float* __restrict__ Wh,
    const float* __restrict__ ax,
    unsigned* __restrict__ home_h, unsigned* __restrict__ home_rh,
    unsigned* __restrict__ lmir_h, unsigned* __restrict__ lmir_rh,
    unsigned* __restrict__ elect, float* __restrict__ outp)
{
  __shared__ float sW[NL][3][RPW][HD];  // 96 KB: h-part weight rows (fp32)
  __shared__ float sVecH[HD];           // staged h (r- and z-dots)
  __shared__ float sVecRH[HD];          // staged r*h (hh-dot)
  __shared__ float sHF32[RPW];          // OWN h rows, fp32 carry
  __shared__ float sAxRZ[2 * RPW];
  __shared__ float sAxH[RPW];
  __shared__ float sZ[RPW];
  __shared__ int   sIsRelay;

  const int wg = blockIdx.x;
  const int tid = threadIdx.x;
  const int row0 = wg * RPW;

  unsigned myxcd;
  asm("s_getreg_b32 %0, hwreg(HW_REG_XCC_ID)" : "=s"(myxcd));
  myxcd &= (NXCD - 1);

  // Stage weights once: h-part = columns [0, HD) of W_g[l][row]
  for (int f = tid; f < NL * 3 * RPW * HD; f += TPB) {
    const int k  = f & (HD - 1);
    const int rr = f >> 10;          // 0..23
    const int r  = rr & 3;
    const int g  = (rr >> 2) % 3;
    const int l  = (rr >> 2) / 3;
    const float* W = (g == 0 ? Wr : (g == 1 ? Wz : Wh));
    sW[l][g][r][k] = W[((size_t)l * HD + row0 + r) * (2 * HD) + k];
  }
  if (tid == 0)   // relay election: first WG per XCD to CAS wins
    sIsRelay = (atomicCAS(&elect[myxcd], 0u, (unsigned)wg + 1u) == 0u);
  if (tid < RPW) sHF32[tid] = 0.0f;    // h0 = 0 (own rows, fp32)
  __syncthreads();
  const bool isRelay = (sIsRelay != 0);

  if (tid < CTH) {
    // ------------------------- compute waves 0-3 -------------------------
    float4 nax_r, nax_z, axh;
    if (tid == 0) {
      nax_r = *reinterpret_cast<const float4*>(&ax[(size_t)0 * SEQ * HD + row0]);
      nax_z = *reinterpret_cast<const float4*>(&ax[(size_t)1 * SEQ * HD + row0]);
    }
    for (int u = 0; u < NSTEP; ++u) {
      const int l = u >> 11;
      const int t = u & (SEQ - 1);
      const unsigned pb  = (unsigned)(u & 1) * NXCD * HD + myxcd * HD;
      const unsigned pbn = (unsigned)((u + 1) & 1) * NXCD * HD;

      // ---- phase 1: poll h; r-dot; publish r*h; z-dot in store shadow ---
      if (tid == 0) {
        sAxRZ[0] = nax_r.x; sAxRZ[1] = nax_r.y; sAxRZ[2] = nax_r.z; sAxRZ[3] = nax_r.w;
        sAxRZ[4] = nax_z.x; sAxRZ[5] = nax_z.y; sAxRZ[6] = nax_z.z; sAxRZ[7] = nax_z.w;
      }
      u32x4 hv = cpoll(lmir_h + pb + 4 * tid, home_h + pb + 4 * tid, (unsigned)u);
      sVecH[4 * tid + 0] = unpackbf(hv.x);
      sVecH[4 * tid + 1] = unpackbf(hv.y);
      sVecH[4 * tid + 2] = unpackbf(hv.z);
      sVecH[4 * tid + 3] = unpackbf(hv.w);
      if (tid == 0) {   // issue ax_h AFTER poll (poll's vmcnt(0) would drain it)
        axh = *reinterpret_cast<const float4*>(
            &ax[(((size_t)l * 3 + 2) * SEQ + t) * HD + row0]);
      }
      __syncthreads();                          // B1
      {
        const int task = tid >> 6;
        const int lane = tid & 63;
        const float* wr_ = sW[l][0][task];
        float sum = 0.0f;
#pragma unroll 8
        for (int k = lane; k < HD; k += 64) sum += wr_[k] * sVecH[k];
#pragma unroll
        for (int off = 32; off; off >>= 1) sum += __shfl_down(sum, off);
        if (lane == 0) {
          const float r = 1.0f / (1.0f + expf(-(sum + sAxRZ[task])));
          publish(home_rh + (unsigned)(u & 1) * NXCD * HD + row0 + task,
                  packbf(r * sHF32[task], (unsigned)(u + 1)), wg);
        }
        const float* wz_ = sW[l][1][task];      // z-dot in the store shadow
        float sz = 0.0f;
#pragma unroll 8
        for (int k = lane; k < HD; k += 64) sz += wz_[k] * sVecH[k];
#pragma unroll
        for (int off = 32; off; off >>= 1) sz += __shfl_down(sz, off);
        if (lane == 0)
          sZ[task] = 1.0f / (1.0f + expf(-(sz + sAxRZ[4 + task])));
      }

      // ---- phase 2: poll r*h; hh-dot; blend; publish h -------------------
      if (tid == 0) {
        sAxH[0] = axh.x; sAxH[1] = axh.y; sAxH[2] = axh.z; sAxH[3] = axh.w;
      }
      u32x4 rv = cpoll(lmir_rh + pb + 4 * tid, home_rh + pb + 4 * tid,
                       (unsigned)(u + 1));
      sVecRH[4 * tid + 0] = unpackbf(rv.x);
      sVecRH[4 * tid + 1] = unpackbf(rv.y);
      sVecRH[4 * tid + 2] = unpackbf(rv.z);
      sVecRH[4 * tid + 3] = unpackbf(rv.w);
      __syncthreads();                          // B2
      {
        const int task = tid >> 6;
        const int lane = tid & 63;
        const float* wh_ = sW[l][2][task];
        float sum = 0.0f;
#pragma unroll 8
        for (int k = lane; k < HD; k += 64) sum += wh_[k] * sVecRH[k];
#pragma unroll
        for (int off = 32; off; off >>= 1) sum += __shfl_down(sum, off);
        if (lane == 0) {
          const float hh = tanhf(sum + sAxH[task]);
          const float z = sZ[task];
          const float hn = (1.0f - z) * sHF32[task] + z * hh;   // fp32 carry
          sHF32[task] = hn;
          publish(home_h + pbn + row0 + task, packbf(hn, (unsigned)(u + 1)), wg);
          if (u == NSTEP - 1) {                 // (output, hidden) identical
            outp[row0 + task] = hn;
            outp[HD + row0 + task] = hn;
          }
        }
      }
      if (tid == 0) {   // prefetch next step's ax_r/ax_z (consumed next B1)
        const int un = (u + 1 < NSTEP) ? u + 1 : u;
        const int ln = un >> 11, tn = un & (SEQ - 1);
        nax_r = *reinterpret_cast<const float4*>(
            &ax[(((size_t)ln * 3 + 0) * SEQ + tn) * HD + row0]);
        nax_z = *reinterpret_cast<const float4*>(
            &ax[(((size_t)ln * 3 + 1) * SEQ + tn) * HD + row0]);
      }
    }
  } else {
    // ------------------------- wave 4: relay / idle -----------------------
    const int lane = tid - CTH;
    if (isRelay) {
      for (int u = 0; u < NSTEP; ++u) {
        const unsigned pb = (unsigned)(u & 1) * NXCD * HD + myxcd * HD;
        relay_forward(home_h + pb, lmir_h + pb, (unsigned)u, lane);
        __syncthreads();                        // B1
        relay_forward(home_rh + pb, lmir_rh + pb, (unsigned)(u + 1), lane);
        __syncthreads();                        // B2
      }
    } else {
      for (int u = 0; u < NSTEP; ++u) { __syncthreads(); __syncthreads(); }
    }
  }
}

// ---------------------------------------------------------------------------
extern "C" void kernel_launch(void* const* d_in, const int* in_sizes, int n_in,
                              void* d_out, int out_size, void* d_ws, size_t ws_size,
                              hipStream_t stream) {
  const float* emb = (const float*)d_in[0];
  const float* Wr  = (const float*)d_in[1];
  const float* br  = (const float*)d_in[2];
  const float* Wz  = (const float*)d_in[3];
  const float* bz  = (const float*)d_in[4];
  const float* Wh  = (const float*)d_in[5];
  const float* bh  = (const float*)d_in[6];
  float* outp = (float*)d_out;

  float*    ws      = (float*)d_ws;
  float*    ax      = ws;                                 // 6*SEQ*HD fp32 = 50.3 MB
  unsigned* home_h  = (unsigned*)(ws + (size_t)6 * SEQ * HD);  // 64 KB
  unsigned* home_rh = home_h  + 2 * NXCD * HD;            // 64 KB
  unsigned* lmir_h  = home_rh + 2 * NXCD * HD;            // 64 KB
  unsigned* lmir_rh = lmir_h  + 2 * NXCD * HD;            // 64 KB
  unsigned* elect   = lmir_rh + 2 * NXCD * HD;            // 8 u32 (+pad)

  // Deterministic state each call: zero homes, mirrors (tag0 == valid h0=0)
  // and the election array (graph replays must re-elect from scratch).
  hipMemsetAsync(home_h, 0, (8 * NXCD * HD + 64) * sizeof(unsigned), stream);

  // Phase A: x-part contributions + bias, all gates/layers (parallel GEMM)
  dim3 g1(HD / 64, SEQ / 64, 6);
  ax_gemm_kernel<<<g1, 256, 0, stream>>>(emb, Wr, Wz, Wh, br, bz, bh, ax);

  // Phase B: serial scan; cooperative launch guarantees 256 blocks on 256
  // distinct CUs (1/CU by LDS) => exactly 32 WGs per XCD => election safe.
  void* args[] = {(void*)&Wr, (void*)&Wz, (void*)&Wh, (void*)&ax,
                  (void*)&home_h, (void*)&home_rh, (void*)&lmir_h, (void*)&lmir_rh,
                  (void*)&elect, (void*)&outp};
  hipLaunchCooperativeKernel((const void*)gru_seq_kernel, dim3(NWG), dim3(TPB),
                             args, 0, stream);
}